// Round 14
// baseline (1648.666 us; speedup 1.0000x reference)
//
#include <hip/hip_runtime.h>
#include <hip/hip_bf16.h>

// VQ-VAE encoder, round 14: r12/r13 pipeline with DOUBLE-BUFFERED X tile in
// conv_mfma: per cc, issue raw loads for cc+1 early, MFMA on buf[cur] (r12
// inner loop verbatim), then split3+write buf[cur^1], one barrier. Staging
// latency + split VALU hide under MFMA. Everything else r13 verbatim.

#define B_   32
#define T_   4096
#define E_   256
#define CIN_ 12
#define LM_  4096

typedef __attribute__((ext_vector_type(4))) float f32x4;
typedef __attribute__((ext_vector_type(8))) short bf16x8;
typedef __attribute__((ext_vector_type(8))) unsigned short u16x8;

__device__ __forceinline__ unsigned int bf_rne(float v) {
  unsigned int u = __float_as_uint(v);
  return (u + 0x7fffu + ((u >> 16) & 1u)) >> 16;
}
__device__ __forceinline__ void split2(float v, unsigned short& h, unsigned short& l) {
  unsigned int hu = bf_rne(v);
  h = (unsigned short)hu;
  l = (unsigned short)bf_rne(v - __uint_as_float(hu << 16));
}
__device__ __forceinline__ void split3(float v, unsigned short& a,
                                       unsigned short& b, unsigned short& c) {
  unsigned int h = bf_rne(v);
  a = (unsigned short)h;
  float r1 = v - __uint_as_float(h << 16);
  unsigned int m = bf_rne(r1);
  b = (unsigned short)m;
  float r2 = r1 - __uint_as_float(m << 16);
  c = (unsigned short)bf_rne(r2);
}

// ---- prep_w (r12 verbatim) ----
__global__ __launch_bounds__(256) void prep_w_kernel(
    const float* __restrict__ w, unsigned short* __restrict__ wh,
    unsigned short* __restrict__ wm, unsigned short* __restrict__ wl) {
  const int g = blockIdx.x * 256 + threadIdx.x;
  const int coff  = g & 31;
  const int e     = (g >> 5) & 255;
  const int slice = g >> 13;
  const int cc = slice >> 2, kt = slice & 3;
  const int c = cc * 32 + coff;
  unsigned short h, m, l;
  split3(w[(size_t)e * 1024 + (size_t)c * 4 + kt], h, m, l);
  const size_t o = (size_t)slice * 8192 + (size_t)e * 32 + coff;
  wh[o] = h; wm[o] = m; wl[o] = l;
}

// ---- conv1 (r12 verbatim) ----
__global__ __launch_bounds__(256) void conv1_kernel(
    const float* __restrict__ x, const float* __restrict__ w1,
    const float* __restrict__ b1, float* __restrict__ out_main,
    float* __restrict__ out_tail) {
  __shared__ __align__(16) float xs[259][12];
  __shared__ __align__(16) float wsh[E_ * 48];
  __shared__ float bs[E_];
  const int tid = threadIdx.x;
  const int b = blockIdx.y;
  const int l0 = blockIdx.x * 256;
  for (int idx = tid; idx < 259 * 12; idx += 256) {
    int r = idx / 12, c = idx - r * 12;
    int t = l0 - 2 + r;
    xs[r][c] = (t >= 0 && t < T_) ? x[((size_t)b * T_ + t) * CIN_ + c] : 0.f;
  }
  for (int idx = tid; idx < E_ * 48; idx += 256) wsh[idx] = w1[idx];
  bs[tid] = b1[tid];
  __syncthreads();
  float xr[4][12];
  #pragma unroll
  for (int r = 0; r < 4; ++r)
    #pragma unroll
    for (int c = 0; c < 12; ++c) xr[r][c] = xs[tid + r][c];
  const int l = l0 + tid;
  for (int e = 0; e < E_; ++e) {
    float acc = bs[e];
    #pragma unroll
    for (int c = 0; c < 12; ++c) {
      const float4 wv = *(const float4*)&wsh[e * 48 + c * 4];
      acc += wv.x * xr[0][c] + wv.y * xr[1][c] + wv.z * xr[2][c] + wv.w * xr[3][c];
    }
    if (l < LM_)       out_main[((size_t)b * E_ + e) * LM_ + l] = acc;
    else if (l == LM_) out_tail[(size_t)b * E_ + e] = acc;
  }
}

// ---- BN stats two-pass (r12 verbatim) ----
__global__ __launch_bounds__(256) void bn_pass1(
    const float* __restrict__ hmain, const float* __restrict__ htail,
    float* __restrict__ psum, float* __restrict__ psq) {
  const int bx = blockIdx.x;
  const int c = bx >> 3, sl = bx & 7;
  const int tid = threadIdx.x;
  float s = 0.f, s2 = 0.f;
  for (int b = 0; b < B_; ++b) {
    const float* p = hmain + ((size_t)b * E_ + c) * LM_ + sl * 512;
    const float v0 = p[tid], v1 = p[tid + 256];
    s += v0 + v1;
    s2 += v0 * v0 + v1 * v1;
  }
  if (htail && sl == 7 && tid < B_) {
    const float v = htail[(size_t)tid * E_ + c];
    s += v; s2 += v * v;
  }
  __shared__ float sh[256], sh2[256];
  sh[tid] = s; sh2[tid] = s2; __syncthreads();
  for (int off = 128; off > 0; off >>= 1) {
    if (tid < off) { sh[tid] += sh[tid + off]; sh2[tid] += sh2[tid + off]; }
    __syncthreads();
  }
  if (tid == 0) { psum[bx] = sh[0]; psq[bx] = sh2[0]; }
}

__global__ __launch_bounds__(256) void bn_pass2(
    const float* __restrict__ psum, const float* __restrict__ psq,
    const float* __restrict__ g, const float* __restrict__ be,
    float* __restrict__ scale, float* __restrict__ shift, int hasTail) {
  const int c = threadIdx.x;
  double s = 0.0, s2 = 0.0;
  #pragma unroll
  for (int i = 0; i < 8; ++i) { s += psum[c * 8 + i]; s2 += psq[c * 8 + i]; }
  double N = (double)B_ * (double)(LM_ + hasTail);
  double m = s / N, var = s2 / N - m * m;
  double a = (double)g[c] / sqrt(var + 1e-5);
  scale[c] = (float)a;
  shift[c] = (float)((double)be[c] - m * a);
}

// ---- MFMA conv: double-buffered X, r12 inner MFMA loop ----
template <int MODE>
__global__ __launch_bounds__(256) void conv_mfma(
    const float* __restrict__ in_main, const float* __restrict__ in_tail,
    const unsigned short* __restrict__ wh, const unsigned short* __restrict__ wm,
    const unsigned short* __restrict__ wl, const float* __restrict__ bias,
    const float* __restrict__ scale, const float* __restrict__ shift,
    float* __restrict__ out, float* __restrict__ out_tail, int pad) {
  __shared__ __align__(16) char Xb[2][3][8448];   // [buf][plane h/m/l][132*64]
  __shared__ float sc_sh[E_], sf_sh[E_];
  const int tid = threadIdx.x, lane = tid & 63, wv = tid >> 6;
  const int q = lane >> 4, n16 = lane & 15;
  const int b = blockIdx.z, e0 = blockIdx.y * 128, l0 = blockIdx.x * 128;
  const int eB = e0 + (wv & 1) * 64;
  const int lB = (wv >> 1) * 64;
  sc_sh[tid] = scale[tid]; sf_sh[tid] = shift[tid];

  f32x4 acc[4][4];
  #pragma unroll
  for (int i = 0; i < 4; ++i)
    #pragma unroll
    for (int j = 0; j < 4; ++j) acc[i][j] = (f32x4){0.f, 0.f, 0.f, 0.f};

  const float* inb = in_main + (size_t)b * E_ * LM_;
  const float* intb = in_tail ? (in_tail + (size_t)b * E_) : nullptr;

  // raw loads for staging task idx of chunk cc (no BN; zero/garbage at bounds,
  // validity re-derived in writeTask)
  auto loadTask = [&](int idx, int cc, f32x4& va, f32x4& vb) {
    const int cp = idx & 15, uq = idx >> 4;
    const int c = cc * 32 + cp * 2;
    const int u0 = uq * 4;
    const int lb = l0 - pad + u0;
    const float* pa = inb + (size_t)c * LM_;
    const float* pb = pa + LM_;
    if (lb >= 0 && lb + 3 < LM_) {
      va = *(const f32x4*)(pa + lb);
      vb = *(const f32x4*)(pb + lb);
    } else {
      #pragma unroll
      for (int s = 0; s < 4; ++s) {
        const int l = lb + s;
        float oa = 0.f, ob = 0.f;
        if (l >= 0 && l < LM_)        { oa = pa[l]; ob = pb[l]; }
        else if (l == LM_ && intb)    { oa = intb[c]; ob = intb[c + 1]; }
        va[s] = oa; vb[s] = ob;
      }
    }
  };
  // BN+ReLU+split3+LDS-write for task idx of chunk cc into buffer nb
  auto writeTask = [&](int idx, int cc, f32x4 va, f32x4 vb, int nb) {
    const int cp = idx & 15, uq = idx >> 4;
    const int c = cc * 32 + cp * 2;
    const int u0 = uq * 4;
    const int lb = l0 - pad + u0;
    const float sca = sc_sh[c], sfa = sf_sh[c];
    const float scb = sc_sh[c + 1], sfb = sf_sh[c + 1];
    const int cg = cp >> 2;
    const int cb4 = (cp & 3) * 4;
    #pragma unroll
    for (int s = 0; s < 4; ++s) {
      const int l = lb + s;
      const bool ok = (l >= 0) && (l < LM_ || (l == LM_ && intb));
      const float fa = ok ? fmaxf(fmaf(va[s], sca, sfa), 0.f) : 0.f;
      const float fb = ok ? fmaxf(fmaf(vb[s], scb, sfb), 0.f) : 0.f;
      unsigned short ha, ma, la, hb, mb, lb2;
      split3(fa, ha, ma, la);
      split3(fb, hb, mb, lb2);
      const int u = u0 + s;
      const int off = u * 64 + ((cg ^ ((u >> 1) & 3)) << 4) + cb4;
      *(unsigned int*)(Xb[nb][0] + off) = (unsigned int)ha | ((unsigned int)hb << 16);
      *(unsigned int*)(Xb[nb][1] + off) = (unsigned int)ma | ((unsigned int)mb << 16);
      *(unsigned int*)(Xb[nb][2] + off) = (unsigned int)la | ((unsigned int)lb2 << 16);
    }
  };

  __syncthreads();                       // sc_sh ready
  // prologue: stage cc=0 into buf0
  {
    f32x4 va, vb;
    #pragma unroll
    for (int s2 = 0; s2 < 3; ++s2) {
      const int idx = tid + s2 * 256;
      if (idx < 528) { loadTask(idx, 0, va, vb); writeTask(idx, 0, va, vb, 0); }
    }
  }
  __syncthreads();

  for (int cc = 0; cc < 8; ++cc) {
    const int cur = cc & 1;
    // T14 issue-early: raw loads for cc+1
    f32x4 pva[3], pvb[3];
    if (cc < 7) {
      #pragma unroll
      for (int s2 = 0; s2 < 3; ++s2) {
        const int idx = tid + s2 * 256;
        if (idx < 528) loadTask(idx, cc + 1, pva[s2], pvb[s2]);
      }
    }
    // MFMA on buf[cur] (r12 inner loop verbatim)
    const char* XhB = Xb[cur][0];
    const char* XmB = Xb[cur][1];
    const char* XlB = Xb[cur][2];
    for (int kt = 0; kt < 4; ++kt) {
      bf16x8 Bh[4], Bm[4], Bl[4];
      #pragma unroll
      for (int ni = 0; ni < 4; ++ni) {
        const int u = lB + ni * 16 + n16 + kt;
        const int off = u * 64 + ((q ^ ((u >> 1) & 3)) << 4);
        Bh[ni] = *(const bf16x8*)(XhB + off);
        Bm[ni] = *(const bf16x8*)(XmB + off);
        Bl[ni] = *(const bf16x8*)(XlB + off);
      }
      const size_t so = (size_t)(cc * 4 + kt) * 8192 + (size_t)q * 8;
      #pragma unroll
      for (int mi = 0; mi < 4; ++mi) {
        const size_t o = so + (size_t)(eB + mi * 16 + n16) * 32;
        const bf16x8 Ah = *(const bf16x8*)(wh + o);
        const bf16x8 Am = *(const bf16x8*)(wm + o);
        const bf16x8 Al = *(const bf16x8*)(wl + o);
        #pragma unroll
        for (int ni = 0; ni < 4; ++ni) {
          acc[mi][ni] = __builtin_amdgcn_mfma_f32_16x16x32_bf16(Ah, Bh[ni], acc[mi][ni], 0, 0, 0);
          acc[mi][ni] = __builtin_amdgcn_mfma_f32_16x16x32_bf16(Ah, Bm[ni], acc[mi][ni], 0, 0, 0);
          acc[mi][ni] = __builtin_amdgcn_mfma_f32_16x16x32_bf16(Am, Bh[ni], acc[mi][ni], 0, 0, 0);
          acc[mi][ni] = __builtin_amdgcn_mfma_f32_16x16x32_bf16(Ah, Bl[ni], acc[mi][ni], 0, 0, 0);
          acc[mi][ni] = __builtin_amdgcn_mfma_f32_16x16x32_bf16(Al, Bh[ni], acc[mi][ni], 0, 0, 0);
          acc[mi][ni] = __builtin_amdgcn_mfma_f32_16x16x32_bf16(Am, Bm[ni], acc[mi][ni], 0, 0, 0);
        }
      }
    }
    // write-late: split + store prefetched tile into buf[cur^1]
    if (cc < 7) {
      #pragma unroll
      for (int s2 = 0; s2 < 3; ++s2) {
        const int idx = tid + s2 * 256;
        if (idx < 528) writeTask(idx, cc + 1, pva[s2], pvb[s2], cur ^ 1);
      }
    }
    __syncthreads();
  }

  #pragma unroll
  for (int mi = 0; mi < 4; ++mi) {
    const int eb4 = eB + mi * 16 + q * 4;
    const f32x4 bv = *(const f32x4*)(bias + eb4);
    #pragma unroll
    for (int ni = 0; ni < 4; ++ni) {
      const int col = l0 + lB + ni * 16 + n16;
      const f32x4 r = acc[mi][ni] + bv;
      if constexpr (MODE == 0) {
        #pragma unroll
        for (int rr = 0; rr < 4; ++rr)
          out[((size_t)b * E_ + eb4 + rr) * LM_ + col] = r[rr];
      } else if constexpr (MODE == 1) {
        if (col < LM_) {
          #pragma unroll
          for (int rr = 0; rr < 4; ++rr)
            out[((size_t)b * E_ + eb4 + rr) * LM_ + col] = r[rr];
        } else if (col == LM_) {
          #pragma unroll
          for (int rr = 0; rr < 4; ++rr)
            out_tail[(size_t)b * E_ + eb4 + rr] = r[rr];
        }
      } else {
        #pragma unroll
        for (int rr = 0; rr < 4; ++rr)
          out[((size_t)b * T_ + col) * E_ + eb4 + rr] = r[rr];
      }
    }
  }
}

// ---- cbprep (r12 verbatim) ----
__global__ __launch_bounds__(256) void cbprep_kernel(
    const float* __restrict__ cb, unsigned short* __restrict__ cbh,
    unsigned short* __restrict__ cbl, float* __restrict__ cnh) {
  const int code = blockIdx.x * 4 + (threadIdx.x >> 6);
  const int lane = threadIdx.x & 63;
  const f32x4 v = *(const f32x4*)&cb[(size_t)code * E_ + lane * 4];
  ushort4 h, l;
  split2(v.x, h.x, l.x); split2(v.y, h.y, l.y);
  split2(v.z, h.z, l.z); split2(v.w, h.w, l.w);
  *(ushort4*)&cbh[(size_t)code * E_ + lane * 4] = h;
  *(ushort4*)&cbl[(size_t)code * E_ + lane * 4] = l;
  float s = v.x * v.x + v.y * v.y + v.z * v.z + v.w * v.w;
  for (int off = 32; off > 0; off >>= 1) s += __shfl_xor(s, off, 64);
  if (lane == 0) cnh[code] = 0.5f * s;
}

// ---- MFMA VQ (r12 verbatim: LDS-staged, double-buffered) ----
__global__ __launch_bounds__(256) void vq_mfma_kernel(
    const float* __restrict__ z, const unsigned short* __restrict__ cbh,
    const unsigned short* __restrict__ cbl, const float* __restrict__ cnh,
    int* __restrict__ ids) {
  __shared__ __align__(16) char cbLds[2][16384];
  __shared__ float cn_sh[1024];
  const int tid = threadIdx.x;
  const int lane = tid & 63;
  const int w = tid >> 6;
  const int q = lane >> 4;
  const int m15 = lane & 15;
  const int rbase = blockIdx.x * 128 + w * 32;
  for (int i = tid; i < 1024; i += 256) cn_sh[i] = cnh[i];

  const int sc0 = tid >> 5, sl0 = tid & 31;
  const int sc1 = (tid + 256) >> 5, sl1 = (tid + 256) & 31;
  const int d0 = sc0 * 512 + (((sl0 ^ (sc0 & 7))) << 4);
  const int d1 = sc1 * 512 + (((sl1 ^ (sc1 & 7))) << 4);
  const u16x8* srcH = (const u16x8*)cbh;
  const u16x8* srcL = (const u16x8*)cbl;

  {
    u16x8 h0 = srcH[tid], h1 = srcH[tid + 256];
    u16x8 l0 = srcL[tid], l1 = srcL[tid + 256];
    *(u16x8*)(cbLds[0] + d0) = h0;
    *(u16x8*)(cbLds[0] + d1) = h1;
    *(u16x8*)(cbLds[0] + 8192 + d0) = l0;
    *(u16x8*)(cbLds[0] + 8192 + d1) = l1;
  }

  bf16x8 zh[2][8], zl[2][8];
  #pragma unroll
  for (int g = 0; g < 2; ++g) {
    const int row = rbase + g * 16 + m15;
    const float* zr = z + (size_t)row * 256 + q * 8;
    #pragma unroll
    for (int ec = 0; ec < 8; ++ec) {
      const f32x4 v0 = *(const f32x4*)(zr + ec * 32);
      const f32x4 v1 = *(const f32x4*)(zr + ec * 32 + 4);
      u16x8 h, l;
      #pragma unroll
      for (int j = 0; j < 4; ++j) {
        unsigned short a, b;
        split2(v0[j], a, b); h[j] = a; l[j] = b;
        split2(v1[j], a, b); h[4 + j] = a; l[4 + j] = b;
      }
      zh[g][ec] = (bf16x8)h;
      zl[g][ec] = (bf16x8)l;
    }
  }
  __syncthreads();

  float best[2] = {-3.4e38f, -3.4e38f};
  int bidx[2] = {0, 0};
  const int swz = (m15 & 7) << 4;
  const int rowOff = m15 * 512;

  for (int cg = 0; cg < 64; ++cg) {
    const int cur = cg & 1;
    u16x8 ph0, ph1, pl0, pl1;
    if (cg < 63) {
      const int sb = (cg + 1) * 512;
      ph0 = srcH[sb + tid]; ph1 = srcH[sb + tid + 256];
      pl0 = srcL[sb + tid]; pl1 = srcL[sb + tid + 256];
    }
    const char* baseH = cbLds[cur];
    const char* baseL = cbLds[cur] + 8192;
    f32x4 ahh[2], ahl[2], alh[2];
    #pragma unroll
    for (int g = 0; g < 2; ++g) {
      ahh[g] = (f32x4){0.f, 0.f, 0.f, 0.f};
      ahl[g] = (f32x4){0.f, 0.f, 0.f, 0.f};
      alh[g] = (f32x4){0.f, 0.f, 0.f, 0.f};
    }
    #pragma unroll
    for (int ec = 0; ec < 8; ++ec) {
      const int co = rowOff + ((q * 16 + ec * 64) ^ swz);
      const bf16x8 Ah = *(const bf16x8*)(baseH + co);
      const bf16x8 Al = *(const bf16x8*)(baseL + co);
      #pragma unroll
      for (int g = 0; g < 2; ++g) {
        ahh[g] = __builtin_amdgcn_mfma_f32_16x16x32_bf16(Ah, zh[g][ec], ahh[g], 0, 0, 0);
        ahl[g] = __builtin_amdgcn_mfma_f32_16x16x32_bf16(Ah, zl[g][ec], ahl[g], 0, 0, 0);
        alh[g] = __builtin_amdgcn_mfma_f32_16x16x32_bf16(Al, zh[g][ec], alh[g], 0, 0, 0);
      }
    }
    const f32x4 cn = *(const f32x4*)&cn_sh[cg * 16 + q * 4];
    #pragma unroll
    for (int g = 0; g < 2; ++g) {
      #pragma unroll
      for (int r = 0; r < 4; ++r) {
        const float s = (ahh[g][r] + ahl[g][r]) + alh[g][r] - cn[r];
        const int code = cg * 16 + q * 4 + r;
        if (s > best[g]) { best[g] = s; bidx[g] = code; }
      }
    }
    if (cg < 63) {
      char* nb = cbLds[cur ^ 1];
      *(u16x8*)(nb + d0) = ph0;
      *(u16x8*)(nb + d1) = ph1;
      *(u16x8*)(nb + 8192 + d0) = pl0;
      *(u16x8*)(nb + 8192 + d1) = pl1;
    }
    __syncthreads();
  }

  #pragma unroll
  for (int g = 0; g < 2; ++g) {
    #pragma unroll
    for (int off = 16; off <= 32; off <<= 1) {
      const float ov = __shfl_xor(best[g], off, 64);
      const int oi = __shfl_xor(bidx[g], off, 64);
      if (ov > best[g] || (ov == best[g] && oi < bidx[g])) { best[g] = ov; bidx[g] = oi; }
    }
  }
  if (q == 0) {
    #pragma unroll
    for (int g = 0; g < 2; ++g) ids[rbase + g * 16 + lane] = bidx[g];
  }
}

// ---- gather (r12 verbatim) ----
__global__ __launch_bounds__(256) void gather_kernel(
    const int* __restrict__ ids, const float* __restrict__ cb,
    float* __restrict__ zq) {
  const int row = blockIdx.x * 4 + (threadIdx.x >> 6);
  const int lane = threadIdx.x & 63;
  const int id = ids[row];
  const float4 v = *(const float4*)&cb[(size_t)id * E_ + lane * 4];
  *(float4*)&zq[(size_t)row * E_ + lane * 4] = v;
}

extern "C" void kernel_launch(void* const* d_in, const int* in_sizes, int n_in,
                              void* d_out, int out_size, void* d_ws, size_t ws_size,
                              hipStream_t stream) {
  const float* x   = (const float*)d_in[0];
  const float* w1  = (const float*)d_in[1];
  const float* b1  = (const float*)d_in[2];
  const float* g1  = (const float*)d_in[3];
  const float* be1 = (const float*)d_in[4];
  const float* w2  = (const float*)d_in[5];
  const float* b2  = (const float*)d_in[6];
  const float* g2  = (const float*)d_in[7];
  const float* be2 = (const float*)d_in[8];
  const float* w3  = (const float*)d_in[9];
  const float* b3  = (const float*)d_in[10];
  const float* g3  = (const float*)d_in[11];
  const float* be3 = (const float*)d_in[12];
  const float* w4  = (const float*)d_in[13];
  const float* b4  = (const float*)d_in[14];
  const float* cb  = (const float*)d_in[15];

  char* ws = (char*)d_ws;
  float* tailA  = (float*)(ws);
  float* scale1 = (float*)(ws + 40960);  float* shift1 = (float*)(ws + 45056);
  float* scale2 = (float*)(ws + 49152);  float* shift2 = (float*)(ws + 53248);
  float* scale3 = (float*)(ws + 57344);  float* shift3 = (float*)(ws + 61440);
  float* cnh    = (float*)(ws + 65536);
  float* psum   = (float*)(ws + 73728);
  float* psq    = (float*)(ws + 81920);
  int*   ids    = (int*)(ws + 131072);
  const size_t MB = 1u << 20;
  unsigned short* wh2 = (unsigned short*)(ws + MB);
  unsigned short* wm2 = (unsigned short*)(ws + MB + 524288u);
  unsigned short* wl2 = (unsigned short*)(ws + MB + 1048576u);
  unsigned short* wh3 = (unsigned short*)(ws + MB + 1572864u);
  unsigned short* wm3 = (unsigned short*)(ws + MB + 2097152u);
  unsigned short* wl3 = (unsigned short*)(ws + MB + 2621440u);
  unsigned short* wh4 = (unsigned short*)(ws + MB + 3145728u);
  unsigned short* wm4 = (unsigned short*)(ws + MB + 3670016u);
  unsigned short* wl4 = (unsigned short*)(ws + MB + 4194304u);

  float* half1 = (float*)d_out;
  float* half2 = half1 + (size_t)33554432;
  unsigned short* cbh = (unsigned short*)half2;
  unsigned short* cbl = (unsigned short*)half2 + 262144;

  prep_w_kernel<<<1024, 256, 0, stream>>>(w2, wh2, wm2, wl2);
  prep_w_kernel<<<1024, 256, 0, stream>>>(w3, wh3, wm3, wl3);
  prep_w_kernel<<<1024, 256, 0, stream>>>(w4, wh4, wm4, wl4);

  conv1_kernel<<<dim3(17, 32), 256, 0, stream>>>(x, w1, b1, half2, tailA);
  bn_pass1<<<2048, 256, 0, stream>>>(half2, tailA, psum, psq);
  bn_pass2<<<1, 256, 0, stream>>>(psum, psq, g1, be1, scale1, shift1, 1);
  conv_mfma<0><<<dim3(32, 2, 32), 256, 0, stream>>>(half2, tailA, wh2, wm2, wl2, b2,
                                                    scale1, shift1, half1, nullptr, 1);
  bn_pass1<<<2048, 256, 0, stream>>>(half1, nullptr, psum, psq);
  bn_pass2<<<1, 256, 0, stream>>>(psum, psq, g2, be2, scale2, shift2, 0);
  conv_mfma<1><<<dim3(33, 2, 32), 256, 0, stream>>>(half1, nullptr, wh3, wm3, wl3, b3,
                                                    scale2, shift2, half2, tailA, 2);
  bn_pass1<<<2048, 256, 0, stream>>>(half2, tailA, psum, psq);
  bn_pass2<<<1, 256, 0, stream>>>(psum, psq, g3, be3, scale3, shift3, 1);
  conv_mfma<2><<<dim3(32, 2, 32), 256, 0, stream>>>(half2, tailA, wh4, wm4, wl4, b4,
                                                    scale3, shift3, half1, nullptr, 1);
  cbprep_kernel<<<256, 256, 0, stream>>>(cb, cbh, cbl, cnh);
  vq_mfma_kernel<<<1024, 256, 0, stream>>>(half1, cbh, cbl, cnh, ids);
  gather_kernel<<<32768, 256, 0, stream>>>(ids, cb, half2);
}

// Round 15
// 1443.570 us; speedup vs baseline: 1.1421x; 1.1421x over previous
//
#include <hip/hip_runtime.h>
#include <hip/hip_bf16.h>

// VQ-VAE encoder, round 15: r12 pipeline (r14 dbuf reverted) with conv_mfma
// retiled 128ex128l -> 256ex64l: 4 waves = 4 e-strips share ONE X tile, so
// X staging per block halves and eb-duplication disappears; smaller LDS
// (~15KB) + 92 VGPR -> ~5 blocks/CU for inter-block MFMA/staging overlap.
// Inner MFMA loop, staging transform, vq, bn: r12 verbatim.

#define B_   32
#define T_   4096
#define E_   256
#define CIN_ 12
#define LM_  4096

typedef __attribute__((ext_vector_type(4))) float f32x4;
typedef __attribute__((ext_vector_type(8))) short bf16x8;
typedef __attribute__((ext_vector_type(8))) unsigned short u16x8;

__device__ __forceinline__ unsigned int bf_rne(float v) {
  unsigned int u = __float_as_uint(v);
  return (u + 0x7fffu + ((u >> 16) & 1u)) >> 16;
}
__device__ __forceinline__ void split2(float v, unsigned short& h, unsigned short& l) {
  unsigned int hu = bf_rne(v);
  h = (unsigned short)hu;
  l = (unsigned short)bf_rne(v - __uint_as_float(hu << 16));
}
__device__ __forceinline__ void split3(float v, unsigned short& a,
                                       unsigned short& b, unsigned short& c) {
  unsigned int h = bf_rne(v);
  a = (unsigned short)h;
  float r1 = v - __uint_as_float(h << 16);
  unsigned int m = bf_rne(r1);
  b = (unsigned short)m;
  float r2 = r1 - __uint_as_float(m << 16);
  c = (unsigned short)bf_rne(r2);
}

// ---- prep_w (r12 verbatim) ----
__global__ __launch_bounds__(256) void prep_w_kernel(
    const float* __restrict__ w, unsigned short* __restrict__ wh,
    unsigned short* __restrict__ wm, unsigned short* __restrict__ wl) {
  const int g = blockIdx.x * 256 + threadIdx.x;
  const int coff  = g & 31;
  const int e     = (g >> 5) & 255;
  const int slice = g >> 13;
  const int cc = slice >> 2, kt = slice & 3;
  const int c = cc * 32 + coff;
  unsigned short h, m, l;
  split3(w[(size_t)e * 1024 + (size_t)c * 4 + kt], h, m, l);
  const size_t o = (size_t)slice * 8192 + (size_t)e * 32 + coff;
  wh[o] = h; wm[o] = m; wl[o] = l;
}

// ---- conv1 (r12 verbatim) ----
__global__ __launch_bounds__(256) void conv1_kernel(
    const float* __restrict__ x, const float* __restrict__ w1,
    const float* __restrict__ b1, float* __restrict__ out_main,
    float* __restrict__ out_tail) {
  __shared__ __align__(16) float xs[259][12];
  __shared__ __align__(16) float wsh[E_ * 48];
  __shared__ float bs[E_];
  const int tid = threadIdx.x;
  const int b = blockIdx.y;
  const int l0 = blockIdx.x * 256;
  for (int idx = tid; idx < 259 * 12; idx += 256) {
    int r = idx / 12, c = idx - r * 12;
    int t = l0 - 2 + r;
    xs[r][c] = (t >= 0 && t < T_) ? x[((size_t)b * T_ + t) * CIN_ + c] : 0.f;
  }
  for (int idx = tid; idx < E_ * 48; idx += 256) wsh[idx] = w1[idx];
  bs[tid] = b1[tid];
  __syncthreads();
  float xr[4][12];
  #pragma unroll
  for (int r = 0; r < 4; ++r)
    #pragma unroll
    for (int c = 0; c < 12; ++c) xr[r][c] = xs[tid + r][c];
  const int l = l0 + tid;
  for (int e = 0; e < E_; ++e) {
    float acc = bs[e];
    #pragma unroll
    for (int c = 0; c < 12; ++c) {
      const float4 wv = *(const float4*)&wsh[e * 48 + c * 4];
      acc += wv.x * xr[0][c] + wv.y * xr[1][c] + wv.z * xr[2][c] + wv.w * xr[3][c];
    }
    if (l < LM_)       out_main[((size_t)b * E_ + e) * LM_ + l] = acc;
    else if (l == LM_) out_tail[(size_t)b * E_ + e] = acc;
  }
}

// ---- BN stats two-pass (r12 verbatim) ----
__global__ __launch_bounds__(256) void bn_pass1(
    const float* __restrict__ hmain, const float* __restrict__ htail,
    float* __restrict__ psum, float* __restrict__ psq) {
  const int bx = blockIdx.x;
  const int c = bx >> 3, sl = bx & 7;
  const int tid = threadIdx.x;
  float s = 0.f, s2 = 0.f;
  for (int b = 0; b < B_; ++b) {
    const float* p = hmain + ((size_t)b * E_ + c) * LM_ + sl * 512;
    const float v0 = p[tid], v1 = p[tid + 256];
    s += v0 + v1;
    s2 += v0 * v0 + v1 * v1;
  }
  if (htail && sl == 7 && tid < B_) {
    const float v = htail[(size_t)tid * E_ + c];
    s += v; s2 += v * v;
  }
  __shared__ float sh[256], sh2[256];
  sh[tid] = s; sh2[tid] = s2; __syncthreads();
  for (int off = 128; off > 0; off >>= 1) {
    if (tid < off) { sh[tid] += sh[tid + off]; sh2[tid] += sh2[tid + off]; }
    __syncthreads();
  }
  if (tid == 0) { psum[bx] = sh[0]; psq[bx] = sh2[0]; }
}

__global__ __launch_bounds__(256) void bn_pass2(
    const float* __restrict__ psum, const float* __restrict__ psq,
    const float* __restrict__ g, const float* __restrict__ be,
    float* __restrict__ scale, float* __restrict__ shift, int hasTail) {
  const int c = threadIdx.x;
  double s = 0.0, s2 = 0.0;
  #pragma unroll
  for (int i = 0; i < 8; ++i) { s += psum[c * 8 + i]; s2 += psq[c * 8 + i]; }
  double N = (double)B_ * (double)(LM_ + hasTail);
  double m = s / N, var = s2 / N - m * m;
  double a = (double)g[c] / sqrt(var + 1e-5);
  scale[c] = (float)a;
  shift[c] = (float)((double)be[c] - m * a);
}

// ---- MFMA conv: 256e x 64l block, 4 waves = 4 e-strips, shared X tile ----
// MODE 0: out (B,E,4096). MODE 1: main+tail. MODE 2: z (B,T,E).
template <int MODE>
__global__ __launch_bounds__(256) void conv_mfma(
    const float* __restrict__ in_main, const float* __restrict__ in_tail,
    const unsigned short* __restrict__ wh, const unsigned short* __restrict__ wm,
    const unsigned short* __restrict__ wl, const float* __restrict__ bias,
    const float* __restrict__ scale, const float* __restrict__ shift,
    float* __restrict__ out, float* __restrict__ out_tail, int pad) {
  __shared__ __align__(16) char XhB[68 * 64];   // [u][32 bf16], slot-swizzled
  __shared__ __align__(16) char XmB[68 * 64];
  __shared__ __align__(16) char XlB[68 * 64];
  __shared__ float sc_sh[E_], sf_sh[E_];
  const int tid = threadIdx.x, lane = tid & 63, wv = tid >> 6;
  const int q = lane >> 4, n16 = lane & 15;
  const int b = blockIdx.z, l0 = blockIdx.x * 64;
  const int eB = wv * 64;              // wave e-strip
  sc_sh[tid] = scale[tid]; sf_sh[tid] = shift[tid];

  f32x4 acc[4][4];
  #pragma unroll
  for (int i = 0; i < 4; ++i)
    #pragma unroll
    for (int j = 0; j < 4; ++j) acc[i][j] = (f32x4){0.f, 0.f, 0.f, 0.f};

  const float* inb = in_main + (size_t)b * E_ * LM_;
  const float* intb = in_tail ? (in_tail + (size_t)b * E_) : nullptr;

  for (int cc = 0; cc < 8; ++cc) {
    __syncthreads();                   // prior LDS reads done; sc_sh ready (iter 0)
    // ---- stage X: 272 tasks = uquad(17) x cpair(16); BN+ReLU+split3 ----
    for (int idx = tid; idx < 272; idx += 256) {
      const int cp = idx & 15, uq = idx >> 4;
      const int c = cc * 32 + cp * 2;
      const int u0 = uq * 4;
      const int lb = l0 - pad + u0;
      const float* pa = inb + (size_t)c * LM_;
      const float* pb = pa + LM_;
      const float sca = sc_sh[c], sfa = sf_sh[c];
      const float scb = sc_sh[c + 1], sfb = sf_sh[c + 1];
      float fa[4], fb[4];
      if (lb >= 0 && lb + 3 < LM_) {
        const f32x4 va = *(const f32x4*)(pa + lb);
        const f32x4 vb = *(const f32x4*)(pb + lb);
        #pragma unroll
        for (int s = 0; s < 4; ++s) {
          fa[s] = fmaxf(fmaf(va[s], sca, sfa), 0.f);
          fb[s] = fmaxf(fmaf(vb[s], scb, sfb), 0.f);
        }
      } else {
        #pragma unroll
        for (int s = 0; s < 4; ++s) {
          const int l = lb + s;
          float oa = 0.f, ob = 0.f;
          if (l >= 0 && l < LM_) {
            oa = fmaxf(fmaf(pa[l], sca, sfa), 0.f);
            ob = fmaxf(fmaf(pb[l], scb, sfb), 0.f);
          } else if (l == LM_ && intb) {
            oa = fmaxf(fmaf(intb[c], sca, sfa), 0.f);
            ob = fmaxf(fmaf(intb[c + 1], scb, sfb), 0.f);
          }
          fa[s] = oa; fb[s] = ob;
        }
      }
      const int cg = cp >> 2;
      const int cb4 = (cp & 3) * 4;
      #pragma unroll
      for (int s = 0; s < 4; ++s) {
        const int u = u0 + s;
        unsigned short ha, ma, la, hb, mb, lb2;
        split3(fa[s], ha, ma, la);
        split3(fb[s], hb, mb, lb2);
        const int off = u * 64 + ((cg ^ ((u >> 1) & 3)) << 4) + cb4;
        *(unsigned int*)(XhB + off) = (unsigned int)ha | ((unsigned int)hb << 16);
        *(unsigned int*)(XmB + off) = (unsigned int)ma | ((unsigned int)mb << 16);
        *(unsigned int*)(XlB + off) = (unsigned int)la | ((unsigned int)lb2 << 16);
      }
    }
    __syncthreads();                   // X ready
    // ---- MFMA (r12 inner loop; lB removed, eB = wv*64) ----
    for (int kt = 0; kt < 4; ++kt) {
      bf16x8 Bh[4], Bm[4], Bl[4];
      #pragma unroll
      for (int ni = 0; ni < 4; ++ni) {
        const int u = ni * 16 + n16 + kt;
        const int off = u * 64 + ((q ^ ((u >> 1) & 3)) << 4);
        Bh[ni] = *(const bf16x8*)(XhB + off);
        Bm[ni] = *(const bf16x8*)(XmB + off);
        Bl[ni] = *(const bf16x8*)(XlB + off);
      }
      const size_t so = (size_t)(cc * 4 + kt) * 8192 + (size_t)q * 8;
      #pragma unroll
      for (int mi = 0; mi < 4; ++mi) {
        const size_t o = so + (size_t)(eB + mi * 16 + n16) * 32;
        const bf16x8 Ah = *(const bf16x8*)(wh + o);
        const bf16x8 Am = *(const bf16x8*)(wm + o);
        const bf16x8 Al = *(const bf16x8*)(wl + o);
        #pragma unroll
        for (int ni = 0; ni < 4; ++ni) {
          acc[mi][ni] = __builtin_amdgcn_mfma_f32_16x16x32_bf16(Ah, Bh[ni], acc[mi][ni], 0, 0, 0);
          acc[mi][ni] = __builtin_amdgcn_mfma_f32_16x16x32_bf16(Ah, Bm[ni], acc[mi][ni], 0, 0, 0);
          acc[mi][ni] = __builtin_amdgcn_mfma_f32_16x16x32_bf16(Am, Bh[ni], acc[mi][ni], 0, 0, 0);
          acc[mi][ni] = __builtin_amdgcn_mfma_f32_16x16x32_bf16(Ah, Bl[ni], acc[mi][ni], 0, 0, 0);
          acc[mi][ni] = __builtin_amdgcn_mfma_f32_16x16x32_bf16(Al, Bh[ni], acc[mi][ni], 0, 0, 0);
          acc[mi][ni] = __builtin_amdgcn_mfma_f32_16x16x32_bf16(Am, Bm[ni], acc[mi][ni], 0, 0, 0);
        }
      }
    }
  }

  // ---- epilogue: D row = e (q*4+reg), D col = l (n16) ----
  #pragma unroll
  for (int mi = 0; mi < 4; ++mi) {
    const int eb4 = eB + mi * 16 + q * 4;
    const f32x4 bv = *(const f32x4*)(bias + eb4);
    #pragma unroll
    for (int ni = 0; ni < 4; ++ni) {
      const int col = l0 + ni * 16 + n16;
      const f32x4 r = acc[mi][ni] + bv;
      if constexpr (MODE == 0) {
        #pragma unroll
        for (int rr = 0; rr < 4; ++rr)
          out[((size_t)b * E_ + eb4 + rr) * LM_ + col] = r[rr];
      } else if constexpr (MODE == 1) {
        if (col < LM_) {
          #pragma unroll
          for (int rr = 0; rr < 4; ++rr)
            out[((size_t)b * E_ + eb4 + rr) * LM_ + col] = r[rr];
        } else if (col == LM_) {
          #pragma unroll
          for (int rr = 0; rr < 4; ++rr)
            out_tail[(size_t)b * E_ + eb4 + rr] = r[rr];
        }
      } else {
        #pragma unroll
        for (int rr = 0; rr < 4; ++rr)
          out[((size_t)b * T_ + col) * E_ + eb4 + rr] = r[rr];
      }
    }
  }
}

// ---- cbprep (r12 verbatim) ----
__global__ __launch_bounds__(256) void cbprep_kernel(
    const float* __restrict__ cb, unsigned short* __restrict__ cbh,
    unsigned short* __restrict__ cbl, float* __restrict__ cnh) {
  const int code = blockIdx.x * 4 + (threadIdx.x >> 6);
  const int lane = threadIdx.x & 63;
  const f32x4 v = *(const f32x4*)&cb[(size_t)code * E_ + lane * 4];
  ushort4 h, l;
  split2(v.x, h.x, l.x); split2(v.y, h.y, l.y);
  split2(v.z, h.z, l.z); split2(v.w, h.w, l.w);
  *(ushort4*)&cbh[(size_t)code * E_ + lane * 4] = h;
  *(ushort4*)&cbl[(size_t)code * E_ + lane * 4] = l;
  float s = v.x * v.x + v.y * v.y + v.z * v.z + v.w * v.w;
  for (int off = 32; off > 0; off >>= 1) s += __shfl_xor(s, off, 64);
  if (lane == 0) cnh[code] = 0.5f * s;
}

// ---- MFMA VQ (r12 verbatim: LDS-staged, double-buffered) ----
__global__ __launch_bounds__(256) void vq_mfma_kernel(
    const float* __restrict__ z, const unsigned short* __restrict__ cbh,
    const unsigned short* __restrict__ cbl, const float* __restrict__ cnh,
    int* __restrict__ ids) {
  __shared__ __align__(16) char cbLds[2][16384];
  __shared__ float cn_sh[1024];
  const int tid = threadIdx.x;
  const int lane = tid & 63;
  const int w = tid >> 6;
  const int q = lane >> 4;
  const int m15 = lane & 15;
  const int rbase = blockIdx.x * 128 + w * 32;
  for (int i = tid; i < 1024; i += 256) cn_sh[i] = cnh[i];

  const int sc0 = tid >> 5, sl0 = tid & 31;
  const int sc1 = (tid + 256) >> 5, sl1 = (tid + 256) & 31;
  const int d0 = sc0 * 512 + (((sl0 ^ (sc0 & 7))) << 4);
  const int d1 = sc1 * 512 + (((sl1 ^ (sc1 & 7))) << 4);
  const u16x8* srcH = (const u16x8*)cbh;
  const u16x8* srcL = (const u16x8*)cbl;

  {
    u16x8 h0 = srcH[tid], h1 = srcH[tid + 256];
    u16x8 l0 = srcL[tid], l1 = srcL[tid + 256];
    *(u16x8*)(cbLds[0] + d0) = h0;
    *(u16x8*)(cbLds[0] + d1) = h1;
    *(u16x8*)(cbLds[0] + 8192 + d0) = l0;
    *(u16x8*)(cbLds[0] + 8192 + d1) = l1;
  }

  bf16x8 zh[2][8], zl[2][8];
  #pragma unroll
  for (int g = 0; g < 2; ++g) {
    const int row = rbase + g * 16 + m15;
    const float* zr = z + (size_t)row * 256 + q * 8;
    #pragma unroll
    for (int ec = 0; ec < 8; ++ec) {
      const f32x4 v0 = *(const f32x4*)(zr + ec * 32);
      const f32x4 v1 = *(const f32x4*)(zr + ec * 32 + 4);
      u16x8 h, l;
      #pragma unroll
      for (int j = 0; j < 4; ++j) {
        unsigned short a, b;
        split2(v0[j], a, b); h[j] = a; l[j] = b;
        split2(v1[j], a, b); h[4 + j] = a; l[4 + j] = b;
      }
      zh[g][ec] = (bf16x8)h;
      zl[g][ec] = (bf16x8)l;
    }
  }
  __syncthreads();

  float best[2] = {-3.4e38f, -3.4e38f};
  int bidx[2] = {0, 0};
  const int swz = (m15 & 7) << 4;
  const int rowOff = m15 * 512;

  for (int cg = 0; cg < 64; ++cg) {
    const int cur = cg & 1;
    u16x8 ph0, ph1, pl0, pl1;
    if (cg < 63) {
      const int sb = (cg + 1) * 512;
      ph0 = srcH[sb + tid]; ph1 = srcH[sb + tid + 256];
      pl0 = srcL[sb + tid]; pl1 = srcL[sb + tid + 256];
    }
    const char* baseH = cbLds[cur];
    const char* baseL = cbLds[cur] + 8192;
    f32x4 ahh[2], ahl[2], alh[2];
    #pragma unroll
    for (int g = 0; g < 2; ++g) {
      ahh[g] = (f32x4){0.f, 0.f, 0.f, 0.f};
      ahl[g] = (f32x4){0.f, 0.f, 0.f, 0.f};
      alh[g] = (f32x4){0.f, 0.f, 0.f, 0.f};
    }
    #pragma unroll
    for (int ec = 0; ec < 8; ++ec) {
      const int co = rowOff + ((q * 16 + ec * 64) ^ swz);
      const bf16x8 Ah = *(const bf16x8*)(baseH + co);
      const bf16x8 Al = *(const bf16x8*)(baseL + co);
      #pragma unroll
      for (int g = 0; g < 2; ++g) {
        ahh[g] = __builtin_amdgcn_mfma_f32_16x16x32_bf16(Ah, zh[g][ec], ahh[g], 0, 0, 0);
        ahl[g] = __builtin_amdgcn_mfma_f32_16x16x32_bf16(Ah, zl[g][ec], ahl[g], 0, 0, 0);
        alh[g] = __builtin_amdgcn_mfma_f32_16x16x32_bf16(Al, zh[g][ec], alh[g], 0, 0, 0);
      }
    }
    const f32x4 cn = *(const f32x4*)&cn_sh[cg * 16 + q * 4];
    #pragma unroll
    for (int g = 0; g < 2; ++g) {
      #pragma unroll
      for (int r = 0; r < 4; ++r) {
        const float s = (ahh[g][r] + ahl[g][r]) + alh[g][r] - cn[r];
        const int code = cg * 16 + q * 4 + r;
        if (s > best[g]) { best[g] = s; bidx[g] = code; }
      }
    }
    if (cg < 63) {
      char* nb = cbLds[cur ^ 1];
      *(u16x8*)(nb + d0) = ph0;
      *(u16x8*)(nb + d1) = ph1;
      *(u16x8*)(nb + 8192 + d0) = pl0;
      *(u16x8*)(nb + 8192 + d1) = pl1;
    }
    __syncthreads();
  }

  #pragma unroll
  for (int g = 0; g < 2; ++g) {
    #pragma unroll
    for (int off = 16; off <= 32; off <<= 1) {
      const float ov = __shfl_xor(best[g], off, 64);
      const int oi = __shfl_xor(bidx[g], off, 64);
      if (ov > best[g] || (ov == best[g] && oi < bidx[g])) { best[g] = ov; bidx[g] = oi; }
    }
  }
  if (q == 0) {
    #pragma unroll
    for (int g = 0; g < 2; ++g) ids[rbase + g * 16 + lane] = bidx[g];
  }
}

// ---- gather (r12 verbatim) ----
__global__ __launch_bounds__(256) void gather_kernel(
    const int* __restrict__ ids, const float* __restrict__ cb,
    float* __restrict__ zq) {
  const int row = blockIdx.x * 4 + (threadIdx.x >> 6);
  const int lane = threadIdx.x & 63;
  const int id = ids[row];
  const float4 v = *(const float4*)&cb[(size_t)id * E_ + lane * 4];
  *(float4*)&zq[(size_t)row * E_ + lane * 4] = v;
}

extern "C" void kernel_launch(void* const* d_in, const int* in_sizes, int n_in,
                              void* d_out, int out_size, void* d_ws, size_t ws_size,
                              hipStream_t stream) {
  const float* x   = (const float*)d_in[0];
  const float* w1  = (const float*)d_in[1];
  const float* b1  = (const float*)d_in[2];
  const float* g1  = (const float*)d_in[3];
  const float* be1 = (const float*)d_in[4];
  const float* w2  = (const float*)d_in[5];
  const float* b2  = (const float*)d_in[6];
  const float* g2  = (const float*)d_in[7];
  const float* be2 = (const float*)d_in[8];
  const float* w3  = (const float*)d_in[9];
  const float* b3  = (const float*)d_in[10];
  const float* g3  = (const float*)d_in[11];
  const float* be3 = (const float*)d_in[12];
  const float* w4  = (const float*)d_in[13];
  const float* b4  = (const float*)d_in[14];
  const float* cb  = (const float*)d_in[15];

  char* ws = (char*)d_ws;
  float* tailA  = (float*)(ws);
  float* scale1 = (float*)(ws + 40960);  float* shift1 = (float*)(ws + 45056);
  float* scale2 = (float*)(ws + 49152);  float* shift2 = (float*)(ws + 53248);
  float* scale3 = (float*)(ws + 57344);  float* shift3 = (float*)(ws + 61440);
  float* cnh    = (float*)(ws + 65536);
  float* psum   = (float*)(ws + 73728);
  float* psq    = (float*)(ws + 81920);
  int*   ids    = (int*)(ws + 131072);
  const size_t MB = 1u << 20;
  unsigned short* wh2 = (unsigned short*)(ws + MB);
  unsigned short* wm2 = (unsigned short*)(ws + MB + 524288u);
  unsigned short* wl2 = (unsigned short*)(ws + MB + 1048576u);
  unsigned short* wh3 = (unsigned short*)(ws + MB + 1572864u);
  unsigned short* wm3 = (unsigned short*)(ws + MB + 2097152u);
  unsigned short* wl3 = (unsigned short*)(ws + MB + 2621440u);
  unsigned short* wh4 = (unsigned short*)(ws + MB + 3145728u);
  unsigned short* wm4 = (unsigned short*)(ws + MB + 3670016u);
  unsigned short* wl4 = (unsigned short*)(ws + MB + 4194304u);

  float* half1 = (float*)d_out;
  float* half2 = half1 + (size_t)33554432;
  unsigned short* cbh = (unsigned short*)half2;
  unsigned short* cbl = (unsigned short*)half2 + 262144;

  prep_w_kernel<<<1024, 256, 0, stream>>>(w2, wh2, wm2, wl2);
  prep_w_kernel<<<1024, 256, 0, stream>>>(w3, wh3, wm3, wl3);
  prep_w_kernel<<<1024, 256, 0, stream>>>(w4, wh4, wm4, wl4);

  conv1_kernel<<<dim3(17, 32), 256, 0, stream>>>(x, w1, b1, half2, tailA);
  bn_pass1<<<2048, 256, 0, stream>>>(half2, tailA, psum, psq);
  bn_pass2<<<1, 256, 0, stream>>>(psum, psq, g1, be1, scale1, shift1, 1);
  conv_mfma<0><<<dim3(64, 1, 32), 256, 0, stream>>>(half2, tailA, wh2, wm2, wl2, b2,
                                                    scale1, shift1, half1, nullptr, 1);
  bn_pass1<<<2048, 256, 0, stream>>>(half1, nullptr, psum, psq);
  bn_pass2<<<1, 256, 0, stream>>>(psum, psq, g2, be2, scale2, shift2, 0);
  conv_mfma<1><<<dim3(65, 1, 32), 256, 0, stream>>>(half1, nullptr, wh3, wm3, wl3, b3,
                                                    scale2, shift2, half2, tailA, 2);
  bn_pass1<<<2048, 256, 0, stream>>>(half2, tailA, psum, psq);
  bn_pass2<<<1, 256, 0, stream>>>(psum, psq, g3, be3, scale3, shift3, 1);
  conv_mfma<2><<<dim3(64, 1, 32), 256, 0, stream>>>(half2, tailA, wh4, wm4, wl4, b4,
                                                    scale3, shift3, half1, nullptr, 1);
  cbprep_kernel<<<256, 256, 0, stream>>>(cb, cbh, cbl, cnh);
  vq_mfma_kernel<<<1024, 256, 0, stream>>>(half1, cbh, cbl, cnh, ids);
  gather_kernel<<<32768, 256, 0, stream>>>(ids, cb, half2);
}